// Round 1
// 1418.618 us; speedup vs baseline: 1.0534x; 1.0534x over previous
//
#include <hip/hip_runtime.h>
#include <math.h>

#define TPI  4096
#define TT   32768
#define DIN  1176
#define KP   1216          // padded K, divisible by 64 for BK=64 GEMM
#define DM   1024
#define NE   8
#define BN   64
#define NL   4
#define DOUT 4096

typedef __attribute__((ext_vector_type(4))) float floatx4;
typedef __attribute__((ext_vector_type(8))) short bf16x8;
typedef unsigned int uint;

__device__ inline short f2bf(float x) {
    unsigned u = __float_as_uint(x);
    u += 0x7fffu + ((u >> 16) & 1u);
    return (short)(u >> 16);
}
__device__ inline float bf2f(short h) {
    return __uint_as_float(((unsigned)(unsigned short)h) << 16);
}

#define GLP(p) ((const __attribute__((address_space(1))) void*)(p))
#define LDSP(p) ((__attribute__((address_space(3))) void*)(p))
#define ASYNC16(g, s) __builtin_amdgcn_global_load_lds(GLP(g), LDSP(s), 16, 0, 0)

// ws layout (bytes). Xb aliases H1: Xb is dead after gemm_in; H1 first written
// by expert_pair(l=0) which runs strictly after. Total use 158.6 MB (< prior 223.6).
#define OFF_H0    0ul
#define OFF_H1    67108864ul
#define OFF_XB    67108864ul            // alias of H1, 32768*1216*2 = 79,691,776
#define OFF_WBT   146800640ul           // 1024*1216*2
#define OFF_E1T   149291008ul           // 32*64*1024*2
#define OFF_E2T   153485312ul           // 32*1024*64*2
#define OFF_BTOK  157679616ul
#define OFF_BW1   157810688ul
#define OFF_BW2   157941760ul
#define OFF_T2E   158072832ul
#define OFF_T2W   158203904ul
#define OFF_Z     158466048ul
// Z sub-offsets (bytes): 0 counts_pair[256]i | 1024 cursors[256]i | 2048 spare
//   2368 sum_probs[256]f | 3392 mask_cnt[256]f | 4416 g[8192]f | 37184 hsg[512]f
#define Z_BYTES   39232ul
#define OFF_RB    158505280ul
#define OFF_WRT   158506304ul           // bf16 [4][16][1024] = 131072 B

// ---------- convert X (f32) -> Xb (bf16, KP-padded)
__global__ __launch_bounds__(256) void convx_kernel(
    const float* __restrict__ X, short* __restrict__ Xb)
{
    const long row = blockIdx.x;
    const float* src = X + row * (long)DIN;
    short* dst = Xb + row * (long)KP;
    for (int i = threadIdx.x; i < 304; i += 256) {
        short4 s;
        if (i < 294) {
            float4 v = *(const float4*)(src + i * 4);
            s.x = f2bf(v.x); s.y = f2bf(v.y); s.z = f2bf(v.z); s.w = f2bf(v.w);
        } else {
            s.x = 0; s.y = 0; s.z = 0; s.w = 0;
        }
        *(short4*)(dst + i * 4) = s;
    }
}

// ---------- generic transpose: dst[n][k] (row len DK) = src[k][n]
__global__ __launch_bounds__(256) void transp_kernel(
    const float* __restrict__ src, short* __restrict__ dst, int RS, int CS, int DK)
{
    __shared__ float tb[64][65];
    const int kt = blockIdx.x * 64, nt = blockIdx.y * 64;
    const long sb = (long)blockIdx.z * RS * CS;
    const long db = (long)blockIdx.z * CS * DK;
    const int rr = threadIdx.x >> 6, cc = threadIdx.x & 63;
#pragma unroll
    for (int i = 0; i < 16; ++i) {
        int r = i * 4 + rr;
        int k = kt + r, n = nt + cc;
        tb[r][cc] = (k < RS && n < CS) ? src[sb + (long)k * CS + n] : 0.0f;
    }
    __syncthreads();
#pragma unroll
    for (int i = 0; i < 16; ++i) {
        int r = i * 4 + rr;
        int n = nt + r, k = kt + cc;
        if (n < CS && k < DK) dst[db + (long)n * DK + k] = f2bf(tb[cc][r]);
    }
}

// ---------- router weights: wrT[l][16][1024] = w_rimg[l][k][e] transposed, e>=8 zero
__global__ __launch_bounds__(256) void wrt_kernel(
    const float* __restrict__ w_rimg, short* __restrict__ wrT)
{
    const int l = blockIdx.x >> 4, e = blockIdx.x & 15;
    short* dst = wrT + ((long)l * 16 + e) * 1024;
    if (e < 8) {
        const float* src = w_rimg + (long)l * 8192 + e;
        for (int k = threadIdx.x; k < 1024; k += 256) dst[k] = f2bf(src[k * 8]);
    } else {
        for (int k = threadIdx.x; k < 1024; k += 256) dst[k] = 0;
    }
}

// ---------- in_proj MFMA GEMM, BK=64, swizzled staging, fused column-mean
// LDS layout: As/Bs [128 rows][64 k] bf16, row stride 128 B. Linear dest for
// global_load_lds; bank-conflict fix via pre-swizzled GLOBAL source:
// LDS[row][chunk] holds global chunk (chunk ^ (row&7)) (16-B chunks, involution).
__global__ __launch_bounds__(256) void gemm_in_mfma(
    const short* __restrict__ Xb, const short* __restrict__ Wbt,
    short* __restrict__ Hb, float* __restrict__ g)
{
    __shared__ __align__(16) short As[128 * 64];
    __shared__ __align__(16) short Bs[128 * 64];
    const int tid = threadIdx.x;
    const int m0 = blockIdx.x * 128, n0 = blockIdx.y * 128;
    const int w = tid >> 6, lane = tid & 63;
    const int quad = lane >> 4, l15 = lane & 15;
    const int wm = (w >> 1) * 64, wn = (w & 1) * 64;

    floatx4 acc[4][4];
#pragma unroll
    for (int i = 0; i < 4; ++i)
#pragma unroll
        for (int j = 0; j < 4; ++j) acc[i][j] = 0.0f;

    const int r = tid >> 3;                          // staging row 0..31 (+i*32)
    const int gofs = ((tid & 7) ^ (r & 7)) * 8;      // swizzled source chunk
    const short* ap = Xb + (long)(m0 + r) * KP + gofs;
    const short* bp = Wbt + (long)(n0 + r) * KP + gofs;
    short* asd = As + tid * 8;
    short* bsd = Bs + tid * 8;
    const int rx = l15 & 7;                          // read-side swizzle key

    for (int k0 = 0; k0 < KP; k0 += 64) {
        __syncthreads();
#pragma unroll
        for (int i = 0; i < 4; ++i) {
            ASYNC16(ap + (long)i * 32 * KP + k0, asd + i * 2048);
            ASYNC16(bp + (long)i * 32 * KP + k0, bsd + i * 2048);
        }
        __syncthreads();
#pragma unroll
        for (int kk = 0; kk < 2; ++kk) {
            bf16x8 af[4], bfr[4];
#pragma unroll
            for (int i = 0; i < 4; ++i)
                af[i] = *(const bf16x8*)&As[(wm + i * 16 + l15) * 64 + (((kk * 4 + quad)) ^ rx) * 8];
#pragma unroll
            for (int j = 0; j < 4; ++j)
                bfr[j] = *(const bf16x8*)&Bs[(wn + j * 16 + l15) * 64 + (((kk * 4 + quad)) ^ rx) * 8];
#pragma unroll
            for (int i = 0; i < 4; ++i)
#pragma unroll
                for (int j = 0; j < 4; ++j)
                    acc[i][j] = __builtin_amdgcn_mfma_f32_16x16x32_bf16(af[i], bfr[j], acc[i][j], 0, 0, 0);
        }
    }
    // epilogue: store bf16 C and accumulate per-image column means into g
    const int img = m0 >> 12;        // 128-row tiles never straddle an image
#pragma unroll
    for (int j = 0; j < 4; ++j) {
        float cs = 0.0f;
#pragma unroll
        for (int i = 0; i < 4; ++i)
#pragma unroll
            for (int r2 = 0; r2 < 4; ++r2) {
                short hv = f2bf(acc[i][j][r2]);
                Hb[(long)(m0 + wm + i * 16 + quad * 4 + r2) * DM + n0 + wn + j * 16 + l15] = hv;
                cs += bf2f(hv);      // sum rounded values: matches old colmean numerics
            }
        cs += __shfl_xor(cs, 16);
        cs += __shfl_xor(cs, 32);    // combine 4 quads -> 64-row column sum
        if (quad == 0)
            atomicAdd(&g[img * DM + n0 + wn + j * 16 + l15], cs * (1.0f / 4096.0f));
    }
}

// ---------- column mean (final pooled only)
__global__ __launch_bounds__(256) void colmean_kernel(
    const short* __restrict__ Hb, float* __restrict__ outp)
{
    const int col = blockIdx.x * 256 + threadIdx.x;
    const int img = blockIdx.y;
    const int t0 = blockIdx.z * 256;
    const short* p = Hb + ((long)img * TPI + t0) * DM + col;
    float s = 0.0f;
#pragma unroll 8
    for (int t = 0; t < 256; ++t) s += bf2f(p[(long)t * DM]);
    atomicAdd(&outp[img * DM + col], s * (1.0f / 4096.0f));
}

// ---------- skin stage 1
__global__ __launch_bounds__(256) void skin1_kernel(
    const float* __restrict__ g, const float* __restrict__ w_sc1,
    const float* __restrict__ b_sc1, float* __restrict__ hsg)
{
    __shared__ float red[4][64];
    const int img = blockIdx.x;
    const int part = threadIdx.x >> 6, c = threadIdx.x & 63;
    float s = 0.0f;
    for (int i = 0; i < 256; ++i) {
        int d = part * 256 + i;
        s += g[img * DM + d] * w_sc1[d * 64 + c];
    }
    red[part][c] = s;
    __syncthreads();
    if (part == 0) {
        float v = red[0][c] + red[1][c] + red[2][c] + red[3][c] + b_sc1[c];
        hsg[img * 64 + c] = fmaxf(v, 0.0f);
    }
}

// ---------- skin stage 2
__global__ __launch_bounds__(256) void skin2_kernel(
    const float* __restrict__ hsg, const float* __restrict__ w_sc2, const float* __restrict__ b_sc2,
    const float* __restrict__ w_rskin, float* __restrict__ skin_logits_out, float* __restrict__ rb)
{
    __shared__ float l3[24];
    __shared__ float sp[24];
    const int tid = threadIdx.x;
    if (tid < 24) {
        int img = tid / 3, j = tid % 3;
        float s = b_sc2[j];
        for (int c = 0; c < 64; ++c) s += hsg[img * 64 + c] * w_sc2[c * 3 + j];
        l3[tid] = s;
        skin_logits_out[tid] = s;
    }
    __syncthreads();
    if (tid < 8) {
        float v0 = l3[tid * 3], v1 = l3[tid * 3 + 1], v2 = l3[tid * 3 + 2];
        float m = fmaxf(v0, fmaxf(v1, v2));
        float e0 = expf(v0 - m), e1 = expf(v1 - m), e2 = expf(v2 - m);
        float inv = 1.0f / (e0 + e1 + e2);
        sp[tid * 3] = e0 * inv; sp[tid * 3 + 1] = e1 * inv; sp[tid * 3 + 2] = e2 * inv;
    }
    __syncthreads();
    {
        int l = tid >> 6, img = (tid >> 3) & 7, e = tid & 7;
        float s = 0.0f;
#pragma unroll
        for (int c = 0; c < 3; ++c) s += sp[img * 3 + c] * w_rskin[(l * 3 + c) * 8 + e];
        rb[tid] = s;
    }
}

// ---------- MFMA router for layer 0 only (layers 1-3 fused into expert_pair)
__global__ __launch_bounds__(256) void router_kernel(
    const short* __restrict__ Hb, const short* __restrict__ wrT, const float* __restrict__ rb,
    uint* __restrict__ top2e, float* __restrict__ top2w, int* __restrict__ counts_pair,
    float* __restrict__ sum_probs, float* __restrict__ mask_cnt, int l)
{
    __shared__ __align__(16) short As[8 * 64 * 32];   // [c][tok][32]
    __shared__ float lgS[64 * 9];
    const int tid = threadIdx.x;
    const int tok0 = blockIdx.x * 64;
    const int img = tok0 >> 12;
    const int w = tid >> 6, lane = tid & 63;
    const int quad = lane >> 4, l15 = lane & 15;

    const short* rowptr = Hb + (long)(tok0 + w * 16 + (lane >> 2)) * DM + (lane & 3) * 8;
    short* sdst = As + tid * 8;   // + c*2048
    const short* wrl = wrT + (long)l * 16 * 1024 + l15 * 1024 + quad * 8;

    floatx4 acc = 0.0f;
    for (int k0 = 0; k0 < DM; k0 += 256) {
        __syncthreads();
#pragma unroll
        for (int c = 0; c < 8; ++c) ASYNC16(rowptr + k0 + c * 32, sdst + c * 2048);
        __syncthreads();
#pragma unroll
        for (int c = 0; c < 8; ++c) {
            bf16x8 af = *(const bf16x8*)&As[c * 2048 + (w * 16 + l15) * 32 + quad * 8];
            bf16x8 bf = *(const bf16x8*)(wrl + k0 + c * 32);
            acc = __builtin_amdgcn_mfma_f32_16x16x32_bf16(af, bf, acc, 0, 0, 0);
        }
    }
    if (l15 < 8) {
#pragma unroll
        for (int r = 0; r < 4; ++r) lgS[(w * 16 + quad * 4 + r) * 9 + l15] = acc[r];
    }
    __syncthreads();

    if (tid < 64) {
        const int token = tok0 + tid;
        float p[8];
        float mx = -1e30f;
#pragma unroll
        for (int e = 0; e < 8; ++e) {
            float v = lgS[tid * 9 + e] + rb[l * 64 + img * 8 + e];
            p[e] = v; mx = fmaxf(mx, v);
        }
        float s = 0.0f;
#pragma unroll
        for (int e = 0; e < 8; ++e) { p[e] = expf(p[e] - mx); s += p[e]; }
        float inv = 1.0f / s;
#pragma unroll
        for (int e = 0; e < 8; ++e) p[e] *= inv;

        int i1 = 0; float b1v = p[0];
#pragma unroll
        for (int e = 1; e < 8; ++e) if (p[e] > b1v) { b1v = p[e]; i1 = e; }
        int i2 = -1; float b2v = -1.0f;
#pragma unroll
        for (int e = 0; e < 8; ++e) if (e != i1 && p[e] > b2v) { b2v = p[e]; i2 = e; }
        float den = b1v + b2v + 1e-6f;
        top2e[token] = (uint)i1 | ((uint)i2 << 8);
        top2w[2 * token] = b1v / den;
        top2w[2 * token + 1] = b2v / den;

        atomicAdd(&counts_pair[l * 64 + i1 * 8 + i2], 1);

        for (int slot = 0; slot < 2; ++slot) {
            int esel = slot ? i2 : i1;
#pragma unroll
            for (int e = 0; e < 8; ++e) {
                unsigned long long m = __ballot(esel == e);
                int pc = __popcll(m);
                if (pc && tid == (__ffsll(m) - 1))
                    atomicAdd(&mask_cnt[l * 64 + img * 8 + e], (float)pc);
            }
        }
#pragma unroll
        for (int e = 0; e < 8; ++e) {
            float rsum = p[e];
            for (int off = 32; off > 0; off >>= 1) rsum += __shfl_down(rsum, off);
            if (tid == 0) atomicAdd(&sum_probs[l * 64 + img * 8 + e], rsum);
        }
    }
}

// ---------- scatter by expert-pair; pair offsets computed in-block (no wq kernel)
__global__ __launch_bounds__(256) void scatter_kernel(
    const uint* __restrict__ top2e, const float* __restrict__ top2w,
    const int* __restrict__ counts_pair, int* __restrict__ cursors,
    int* __restrict__ btok, float* __restrict__ bw1, float* __restrict__ bw2, int l)
{
    __shared__ int pofS[64];
    const int tid = threadIdx.x;
    if (tid < 64) {
        int c = counts_pair[l * 64 + tid];
        int x = c;
#pragma unroll
        for (int off = 1; off < 64; off <<= 1) {
            int y = __shfl_up(x, off);
            if (tid >= off) x += y;
        }
        pofS[tid] = x - c;
    }
    __syncthreads();
    const int t = blockIdx.x * 256 + tid;
    const int lane = tid & 63;
    uint pe = top2e[t];
    int p = (int)(pe & 255u) * 8 + (int)((pe >> 8) & 255u);
    float w1 = top2w[2 * t], w2 = top2w[2 * t + 1];
    int myoff = pofS[p];
    unsigned long long rem = __ballot(true);
    while (rem) {
        int leader = __ffsll(rem) - 1;
        int pv = __shfl(p, leader);
        unsigned long long m = __ballot(p == pv);
        int basep = 0;
        if (lane == leader) basep = atomicAdd(&cursors[l * 64 + pv], __popcll(m));
        basep = __shfl(basep, leader);
        if (p == pv) {
            int pos = basep + __popcll(m & ((1ull << lane) - 1ull));
            int s = myoff + pos;
            btok[s] = t;
            bw1[s] = w1;
            bw2[s] = w2;
        }
        rem &= ~m;
    }
}

// ---------- fused pair-expert MLP + (for l<3) next-layer router on the output slabs.
// Self-scheduling: per-block 64-pair prefix scan replaces the wq kernel.
__global__ __launch_bounds__(256) void expert_pair(
    const short* __restrict__ Hin, short* __restrict__ Hout,
    int* __restrict__ counts_pair,
    const int* __restrict__ btok, const float* __restrict__ bw1, const float* __restrict__ bw2,
    const short* __restrict__ ew1t, const float* __restrict__ eb1,
    const short* __restrict__ ew2t, const float* __restrict__ eb2,
    const short* __restrict__ wrT, const float* __restrict__ rb,
    uint* __restrict__ top2e, float* __restrict__ top2w,
    float* __restrict__ sum_probs, float* __restrict__ mask_cnt, int l)
{
    __shared__ __align__(16) short As[8 * 64 * 32];   // k-slab / residual / output / logits
    __shared__ __align__(16) short h1a[64 * 72];
    __shared__ __align__(16) short h1b[64 * 72];
    __shared__ int tkS[64];
    __shared__ float w1S[64], w2S[64];
    __shared__ int pofS[64], cntS[64], tpS[64];
    __shared__ int nworkS;
    __shared__ float spLDS[64], mkLDS[64];            // per-item [img][e] aggregation

    const int tid = threadIdx.x;
    const int w = tid >> 6, lane = tid & 63;
    const int quad = lane >> 4, l15 = lane & 15;
    short* sdst = As + tid * 8;   // + c*2048

    // self-scheduling scan (wave 0): token offsets + inclusive tile prefix
    if (tid < 64) {
        int c = counts_pair[l * 64 + tid];
        cntS[tid] = c;
        int x = c;
#pragma unroll
        for (int off = 1; off < 64; off <<= 1) {
            int y = __shfl_up(x, off);
            if (tid >= off) x += y;
        }
        pofS[tid] = x - c;
        int nb = (c + 63) >> 6;
        int t = nb;
#pragma unroll
        for (int off = 1; off < 64; off <<= 1) {
            int y = __shfl_up(t, off);
            if (tid >= off) t += y;
        }
        tpS[tid] = t;
        if (tid == 63) nworkS = t;
    }
    __syncthreads();
    const int nwork = nworkS;

    for (int wi = blockIdx.x; wi < nwork; wi += gridDim.x) {
        int p = 0;
        while (p < 63 && tpS[p] <= wi) ++p;
        const int cnt = cntS[p];
        const int nbp = (cnt + 63) >> 6;
        const int base = (wi - (tpS[p] - nbp)) * 64;
        const int ea = p >> 3, eb = p & 7;
        const int off = pofS[p];

        __syncthreads();
        if (tid < 64) {
            bool valid = (base + tid) < cnt;
            int s = off + base + tid;
            tkS[tid] = valid ? btok[s] : 0;
            w1S[tid] = valid ? bw1[s] : 0.0f;
            w2S[tid] = valid ? bw2[s] : 0.0f;
            spLDS[tid] = 0.0f;
            mkLDS[tid] = 0.0f;
        }
        __syncthreads();
        const int lea = l * 8 + ea, leb = l * 8 + eb;
        const short* rowptr = Hin + (long)tkS[w * 16 + (lane >> 2)] * DM + (lane & 3) * 8;

        // ---- phase 1: h1 = relu(H @ W1 + b1) for both experts
        floatx4 acc1a[4], acc1b[4];
#pragma unroll
        for (int i = 0; i < 4; ++i) { acc1a[i] = 0.0f; acc1b[i] = 0.0f; }
        const short* w1ap = ew1t + ((long)lea * 64 + w * 16 + l15) * DM + quad * 8;
        const short* w1bp = ew1t + ((long)leb * 64 + w * 16 + l15) * DM + quad * 8;

        for (int k0 = 0; k0 < DM; k0 += 256) {
            __syncthreads();
#pragma unroll
            for (int c = 0; c < 8; ++c) ASYNC16(rowptr + k0 + c * 32, sdst + c * 2048);
            __syncthreads();
#pragma unroll
            for (int c = 0; c < 8; ++c) {
                bf16x8 ba = *(const bf16x8*)(w1ap + k0 + c * 32);
                bf16x8 bb = *(const bf16x8*)(w1bp + k0 + c * 32);
#pragma unroll
                for (int i = 0; i < 4; ++i) {
                    bf16x8 af = *(const bf16x8*)&As[c * 2048 + (i * 16 + l15) * 32 + quad * 8];
                    acc1a[i] = __builtin_amdgcn_mfma_f32_16x16x32_bf16(af, ba, acc1a[i], 0, 0, 0);
                    acc1b[i] = __builtin_amdgcn_mfma_f32_16x16x32_bf16(af, bb, acc1b[i], 0, 0, 0);
                }
            }
        }
        {
            float b1av = eb1[lea * BN + w * 16 + l15];
            float b1bv = eb1[leb * BN + w * 16 + l15];
#pragma unroll
            for (int i = 0; i < 4; ++i)
#pragma unroll
                for (int r = 0; r < 4; ++r) {
                    h1a[(i * 16 + quad * 4 + r) * 72 + w * 16 + l15] =
                        f2bf(fmaxf(acc1a[i][r] + b1av, 0.0f));
                    h1b[(i * 16 + quad * 4 + r) * 72 + w * 16 + l15] =
                        f2bf(fmaxf(acc1b[i][r] + b1bv, 0.0f));
                }
        }
        __syncthreads();   // h1 visible; As free

        // ---- phase 2: 4 n-groups of 256 cols; accumulate next-layer logits on the fly
        const short* w2ap = ew2t + ((long)lea * DM + w * 16 + l15) * 64 + quad * 8;
        const short* w2bp = ew2t + ((long)leb * DM + w * 16 + l15) * 64 + quad * 8;
        const bool rowvalid = (base + (tid >> 2)) < cnt;
        const long orow = (long)tkS[tid >> 2] * DM;

        floatx4 acc_lg[4];     // logits partial: [tokf]: C[e=quad*4+r][tok=tokf*16+l15]
#pragma unroll
        for (int tf = 0; tf < 4; ++tf) acc_lg[tf] = 0.0f;

        for (int gidx = 0; gidx < 4; ++gidx) {
            const int g0 = gidx * 256;
            // stage residual slab
#pragma unroll
            for (int c = 0; c < 8; ++c) ASYNC16(rowptr + g0 + c * 32, sdst + c * 2048);
            __syncthreads();
            // 4 n-slices of 64
#pragma unroll
            for (int ns = 0; ns < 4; ++ns) {
                const int n0 = g0 + ns * 64;
                floatx4 a2a[4], a2b[4];
#pragma unroll
                for (int tj = 0; tj < 4; ++tj) { a2a[tj] = 0.0f; a2b[tj] = 0.0f; }
#pragma unroll
                for (int kk = 0; kk < 2; ++kk) {
                    bf16x8 wa = *(const bf16x8*)(w2ap + (long)n0 * 64 + kk * 32);
                    bf16x8 wb = *(const bf16x8*)(w2bp + (long)n0 * 64 + kk * 32);
#pragma unroll
                    for (int tj = 0; tj < 4; ++tj) {
                        bf16x8 ha = *(const bf16x8*)&h1a[(tj * 16 + l15) * 72 + kk * 32 + quad * 8];
                        bf16x8 hb = *(const bf16x8*)&h1b[(tj * 16 + l15) * 72 + kk * 32 + quad * 8];
                        a2a[tj] = __builtin_amdgcn_mfma_f32_16x16x32_bf16(wa, ha, a2a[tj], 0, 0, 0);
                        a2b[tj] = __builtin_amdgcn_mfma_f32_16x16x32_bf16(wb, hb, a2b[tj], 0, 0, 0);
                    }
                }
                const int nloc = ns * 64 + w * 16 + quad * 4;   // col within group
                const int csub = nloc >> 5, cidx = nloc & 31;
                float4 b2av = *(const float4*)&eb2[lea * DM + g0 + nloc];
                float4 b2bv = *(const float4*)&eb2[leb * DM + g0 + nloc];
#pragma unroll
                for (int tj = 0; tj < 4; ++tj) {
                    int tk = tj * 16 + l15;
                    float w1 = w1S[tk], w2 = w2S[tk];
                    short* slot = &As[csub * 2048 + tk * 32 + cidx];
                    short4 res = *(short4*)slot;
                    short4 o;
                    o.x = f2bf(bf2f(res.x) + w1 * (a2a[tj][0] + b2av.x) + w2 * (a2b[tj][0] + b2bv.x));
                    o.y = f2bf(bf2f(res.y) + w1 * (a2a[tj][1] + b2av.y) + w2 * (a2b[tj][1] + b2bv.y));
                    o.z = f2bf(bf2f(res.z) + w1 * (a2a[tj][2] + b2av.z) + w2 * (a2b[tj][2] + b2bv.z));
                    o.w = f2bf(bf2f(res.w) + w1 * (a2a[tj][3] + b2av.w) + w2 * (a2b[tj][3] + b2bv.w));
                    *(short4*)slot = o;
                }
            }
            __syncthreads();   // output slab complete

            // fused next-layer router: wrT rows (A) x output slab (B); wave w owns
            // k-chunks 2w, 2w+1 of this 256-col group; accumulate across groups.
            if (l < 3) {
                const short* wrp = wrT + ((long)(l + 1) * 16 + l15) * 1024 + g0 + w * 64 + quad * 8;
#pragma unroll
                for (int kk = 0; kk < 2; ++kk) {
                    bf16x8 wf = *(const bf16x8*)(wrp + kk * 32);
#pragma unroll
                    for (int tf = 0; tf < 4; ++tf) {
                        bf16x8 of = *(const bf16x8*)&As[(w * 2 + kk) * 2048 + (tf * 16 + l15) * 32 + quad * 8];
                        acc_lg[tf] = __builtin_amdgcn_mfma_f32_16x16x32_bf16(wf, of, acc_lg[tf], 0, 0, 0);
                    }
                }
            }
            // write group: thread -> row tid>>2, col quarter tid&3 (2 sub-slabs x 64B)
            if (rowvalid) {
                const int tok = tid >> 2;
#pragma unroll
                for (int c2 = 0; c2 < 2; ++c2) {
                    const int csub = (tid & 3) * 2 + c2;
#pragma unroll
                    for (int j = 0; j < 4; ++j) {
                        int4 v = *(const int4*)&As[csub * 2048 + tok * 32 + j * 8];
                        *(int4*)(Hout + orow + g0 + csub * 32 + j * 8) = v;
                    }
                }
            }
            __syncthreads();   // As free for next group
        }

        // ---- fused router tail: reduce 4 wave-partials, softmax, top2, atomics
        if (l < 3) {
            float* lgF = (float*)As;     // [w][64 tok][16 e] f32 = 16 KB
#pragma unroll
            for (int tf = 0; tf < 4; ++tf)
                *(floatx4*)&lgF[(w * 64 + tf * 16 + l15) * 16 + quad * 4] = acc_lg[tf];
            __syncthreads();
            if (tid < 64) {
                const bool valid = (base + tid) < cnt;
                const int token = tkS[tid];
                const int img = token >> 12;
                float pb[8]; float mx = -1e30f;
#pragma unroll
                for (int e = 0; e < 8; ++e) {
                    float v = lgF[tid * 16 + e] + lgF[(64 + tid) * 16 + e]
                            + lgF[(128 + tid) * 16 + e] + lgF[(192 + tid) * 16 + e]
                            + rb[(l + 1) * 64 + img * 8 + e];
                    pb[e] = v; mx = fmaxf(mx, v);
                }
                float s = 0.0f;
#pragma unroll
                for (int e = 0; e < 8; ++e) { pb[e] = expf(pb[e] - mx); s += pb[e]; }
                float inv = 1.0f / s;
#pragma unroll
                for (int e = 0; e < 8; ++e) pb[e] *= inv;
                int i1 = 0; float b1v = pb[0];
#pragma unroll
                for (int e = 1; e < 8; ++e) if (pb[e] > b1v) { b1v = pb[e]; i1 = e; }
                int i2 = -1; float b2v = -1.0f;
#pragma unroll
                for (int e = 0; e < 8; ++e) if (e != i1 && pb[e] > b2v) { b2v = pb[e]; i2 = e; }
                if (valid) {
                    float den = b1v + b2v + 1e-6f;
                    top2e[token] = (uint)i1 | ((uint)i2 << 8);
                    top2w[2 * token] = b1v / den;
                    top2w[2 * token + 1] = b2v / den;
                    atomicAdd(&counts_pair[(l + 1) * 64 + i1 * 8 + i2], 1);
#pragma unroll
                    for (int e = 0; e < 8; ++e) atomicAdd(&spLDS[img * 8 + e], pb[e]);
                    atomicAdd(&mkLDS[img * 8 + i1], 1.0f);
                    atomicAdd(&mkLDS[img * 8 + i2], 1.0f);
                }
            }
            __syncthreads();
            if (tid < 64) {
                float v = spLDS[tid];
                if (v != 0.0f) atomicAdd(&sum_probs[(l + 1) * 64 + tid], v);
                float mz = mkLDS[tid];
                if (mz != 0.0f) atomicAdd(&mask_cnt[(l + 1) * 64 + tid], mz);
            }
        }
    }
}

// ---------- vision_proj
__global__ __launch_bounds__(256) void vproj_kernel(
    const float* __restrict__ pooled, const float* __restrict__ w_out,
    const float* __restrict__ b_out, float* __restrict__ outp)
{
    __shared__ float ps[8 * 128];
    const int tid = threadIdx.x;
    const int n = blockIdx.x * 256 + tid;
    const int d0 = blockIdx.y * 128;
#pragma unroll
    for (int i = 0; i < 4; ++i) {
        int idx = tid + i * 256;
        ps[idx] = pooled[(idx >> 7) * DM + d0 + (idx & 127)];
    }
    __syncthreads();
    float acc[8];
    float binit = (blockIdx.y == 0) ? b_out[n] : 0.0f;
#pragma unroll
    for (int img = 0; img < 8; ++img) acc[img] = binit;
    for (int d = 0; d < 128; ++d) {
        float wv = w_out[(long)(d0 + d) * DOUT + n];
#pragma unroll
        for (int img = 0; img < 8; ++img) acc[img] += ps[img * 128 + d] * wv;
    }
#pragma unroll
    for (int img = 0; img < 8; ++img) atomicAdd(&outp[img * DOUT + n], acc[img]);
}

// ---------- aux
__global__ __launch_bounds__(64) void aux_kernel(
    const float* __restrict__ sum_probs, const float* __restrict__ mask_cnt,
    float* __restrict__ outp)
{
    const int tid = threadIdx.x;
    float v = 0.0f;
    if (tid < 32) {
        float s = 0.0f;
#pragma unroll
        for (int e = 0; e < 8; ++e) s += sum_probs[tid * 8 + e] * mask_cnt[tid * 8 + e];
        v = s * (8.0f / (4096.0f * 4096.0f));
    }
    for (int off = 32; off > 0; off >>= 1) v += __shfl_down(v, off);
    if (tid == 0) outp[0] = v;
}

extern "C" void kernel_launch(void* const* d_in, const int* in_sizes, int n_in,
                              void* d_out, int out_size, void* d_ws, size_t ws_size,
                              hipStream_t stream) {
    const float* X       = (const float*)d_in[0];
    const float* w_in    = (const float*)d_in[2];
    const float* w_sc1   = (const float*)d_in[3];
    const float* b_sc1   = (const float*)d_in[4];
    const float* w_sc2   = (const float*)d_in[5];
    const float* b_sc2   = (const float*)d_in[6];
    const float* w_rimg  = (const float*)d_in[7];
    const float* w_rskin = (const float*)d_in[8];
    const float* ew1     = (const float*)d_in[9];
    const float* eb1     = (const float*)d_in[10];
    const float* ew2     = (const float*)d_in[11];
    const float* eb2     = (const float*)d_in[12];
    const float* w_out   = (const float*)d_in[13];
    const float* b_out   = (const float*)d_in[14];

    float* out = (float*)d_out;
    char* ws = (char*)d_ws;

    short* H0   = (short*)(ws + OFF_H0);
    short* H1   = (short*)(ws + OFF_H1);
    short* Xb   = (short*)(ws + OFF_XB);     // aliases H1 (Xb dead before H1 written)
    short* Wbt  = (short*)(ws + OFF_WBT);
    short* ew1t = (short*)(ws + OFF_E1T);
    short* ew2t = (short*)(ws + OFF_E2T);
    int*   btok = (int*)(ws + OFF_BTOK);
    float* bw1  = (float*)(ws + OFF_BW1);
    float* bw2  = (float*)(ws + OFF_BW2);
    uint*  top2e = (uint*)(ws + OFF_T2E);
    float* top2w = (float*)(ws + OFF_T2W);
    int*   counts_pair = (int*)(ws + OFF_Z);
    int*   cursors     = (int*)(ws + OFF_Z + 1024);
    float* sum_probs   = (float*)(ws + OFF_Z + 2368);
    float* mask_cnt    = (float*)(ws + OFF_Z + 3392);
    float* g           = (float*)(ws + OFF_Z + 4416);
    float* hsg         = (float*)(ws + OFF_Z + 37184);
    float* rb          = (float*)(ws + OFF_RB);
    short* wrT         = (short*)(ws + OFF_WRT);

    hipMemsetAsync(d_out, 0, (size_t)out_size * sizeof(float), stream);
    hipMemsetAsync(ws + OFF_Z, 0, Z_BYTES, stream);

    dim3 b256(256);
    convx_kernel<<<TT, b256, 0, stream>>>(X, Xb);
    transp_kernel<<<dim3(19, 16, 1), b256, 0, stream>>>(w_in, Wbt, DIN, DM, KP);
    transp_kernel<<<dim3(16, 1, 32), b256, 0, stream>>>(ew1, ew1t, DM, BN, DM);
    transp_kernel<<<dim3(1, 16, 32), b256, 0, stream>>>(ew2, ew2t, BN, DM, BN);
    wrt_kernel<<<64, b256, 0, stream>>>(w_rimg, wrT);
    gemm_in_mfma<<<dim3(256, 8), b256, 0, stream>>>(Xb, Wbt, H0, g);
    skin1_kernel<<<8, b256, 0, stream>>>(g, w_sc1, b_sc1, hsg);
    skin2_kernel<<<1, b256, 0, stream>>>(hsg, w_sc2, b_sc2, w_rskin, out + 40961, rb);
    router_kernel<<<512, b256, 0, stream>>>(H0, wrT, rb, top2e, top2w,
                                            counts_pair, sum_probs, mask_cnt, 0);

    short* Hc = H0;
    short* Hn = H1;
    for (int l = 0; l < NL; ++l) {
        scatter_kernel<<<128, b256, 0, stream>>>(top2e, top2w, counts_pair, cursors,
                                                 btok, bw1, bw2, l);
        expert_pair<<<576, b256, 0, stream>>>(Hc, Hn, counts_pair, btok, bw1, bw2,
                                              ew1t, eb1, ew2t, eb2, wrT, rb,
                                              top2e, top2w, sum_probs, mask_cnt, l);
        short* tmp = Hc; Hc = Hn; Hn = tmp;
    }
    colmean_kernel<<<dim3(4, 8, 16), b256, 0, stream>>>(Hc, out);
    vproj_kernel<<<dim3(16, 8), b256, 0, stream>>>(out, w_out, b_out, out + 8192);
    aux_kernel<<<1, 64, 0, stream>>>(sum_probs, mask_cnt, out + 40960);
}